// Round 1
// baseline (196.716 us; speedup 1.0000x reference)
//
#include <hip/hip_runtime.h>

// B=16, T=2048, C=HEAD=64. Causal single-head attention, scale = 1/8 folded into Wq.
// ws layout: Qs bf16 [B][T][64] (4MB) | Ks bf16 [B][T][64] (4MB) | Vt bf16 [B][64][T] (4MB) = 12MB

#define Bsz 16
#define Tsz 2048

typedef __attribute__((ext_vector_type(8))) short bf16x8;
typedef __attribute__((ext_vector_type(4))) float f32x4;

__device__ inline unsigned short f2bf(float f) {
  union { float f; unsigned u; } v; v.f = f;
  unsigned r = v.u + 0x7fffu + ((v.u >> 16) & 1u);  // RNE
  return (unsigned short)(r >> 16);
}

// ---- Projection: q = (x Wq^T)*0.125, k = x Wk^T, v = x Wv^T (V stored transposed) ----
__global__ __launch_bounds__(256) void proj_kernel(
    const float* __restrict__ x, const float* __restrict__ Wq,
    const float* __restrict__ Wk, const float* __restrict__ Wv,
    unsigned short* __restrict__ Qs, unsigned short* __restrict__ Ks,
    unsigned short* __restrict__ Vt) {
  __shared__ float Xs[64 * 64];
  __shared__ float WT[3][64 * 65];  // [c][h], pad 65 -> conflict-free reads
  const int b = blockIdx.y;
  const int tbase = blockIdx.x * 64;
  const int tid = threadIdx.x;

  for (int idx = tid; idx < 4096; idx += 256) {
    int h = idx >> 6, c = idx & 63;
    float wq = Wq[idx], wk = Wk[idx], wv = Wv[idx];
    WT[0][c * 65 + h] = wq * 0.125f;  // fold attention scale into Wq
    WT[1][c * 65 + h] = wk;
    WT[2][c * 65 + h] = wv;
  }
  const float* xp = x + ((size_t)b * Tsz + tbase) * 64;
  for (int idx = tid; idx < 4096; idx += 256) Xs[idx] = xp[idx];
  __syncthreads();

  const int h = tid & 63;          // lane -> output channel
  const int r0 = (tid >> 6) * 16;  // wave -> 16 rows
  float qa[16], ka[16], va[16];
#pragma unroll
  for (int i = 0; i < 16; i++) { qa[i] = 0.f; ka[i] = 0.f; va[i] = 0.f; }
  for (int c = 0; c < 64; c++) {
    float wq = WT[0][c * 65 + h];   // 2-way bank alias: free
    float wk = WT[1][c * 65 + h];
    float wv = WT[2][c * 65 + h];
#pragma unroll
    for (int i = 0; i < 16; i++) {
      float xv = Xs[(r0 + i) * 64 + c];  // wave-uniform -> LDS broadcast
      qa[i] += xv * wq; ka[i] += xv * wk; va[i] += xv * wv;
    }
  }
#pragma unroll
  for (int i = 0; i < 16; i++) {
    size_t base = ((size_t)b * Tsz + tbase + r0 + i) * 64 + h;
    Qs[base] = f2bf(qa[i]);
    Ks[base] = f2bf(ka[i]);
  }
  __syncthreads();                 // done reading WT[0]; reuse as V-transpose tile
  float* Vtile = WT[0];            // [h][s] stride 65
#pragma unroll
  for (int i = 0; i < 16; i++) Vtile[h * 65 + r0 + i] = va[i];
  __syncthreads();
  const int s = tid & 63;
  const int h0 = (tid >> 6) * 16;
#pragma unroll
  for (int i = 0; i < 16; i++) {
    Vt[((size_t)b * 64 + h0 + i) * Tsz + tbase + s] = f2bf(Vtile[(h0 + i) * 65 + s]);
  }
}

// ---- Flash attention: 1 block = 64 q-rows (4 waves x 16), key tiles of 64 ----
// No __syncthreads in the k-loop: each wave writes/reads only its own 16 Sp rows.
__global__ __launch_bounds__(256) void flash_kernel(
    const unsigned short* __restrict__ Qs, const unsigned short* __restrict__ Ks,
    const unsigned short* __restrict__ Vt, float* __restrict__ out) {
  const int b = blockIdx.y;
  const int j = blockIdx.x;
  // interleave q-tiles [0,31,1,30,...] so adjacent blocks pair heavy+light (causal balance)
  const int qt = (j & 1) ? (31 - (j >> 1)) : (j >> 1);
  const int qbase = qt * 64;
  const int tid = threadIdx.x;
  const int lane = tid & 63;
  const int w = tid >> 6;
  const int l15 = lane & 15;
  const int quad = lane >> 4;

  __shared__ unsigned short Sp[64][72];  // stride 72 -> 144B rows, 16B-aligned b128 reads

  // Q A-frags: A[m=lane&15][k=quad*8+j], held in regs for the whole block
  const unsigned short* Qrow =
      Qs + ((size_t)b * Tsz + qbase + w * 16 + l15) * 64 + quad * 8;
  bf16x8 aq0 = *(const bf16x8*)(Qrow);
  bf16x8 aq1 = *(const bf16x8*)(Qrow + 32);

  f32x4 O[4];
  float m_i[4], l_i[4];
#pragma unroll
  for (int r = 0; r < 4; r++) {
    O[r] = (f32x4){0.f, 0.f, 0.f, 0.f};
    m_i[r] = -1e30f;
    l_i[r] = 0.f;
  }
  const int qg = qbase + w * 16 + quad * 4;  // + r = this lane's D rows

  for (int kt = 0; kt <= qbase; kt += 64) {
    // ---- S = Q K^T (scale pre-folded) ----
    f32x4 S[4];
#pragma unroll
    for (int nb = 0; nb < 4; nb++) {
      const unsigned short* Kp =
          Ks + ((size_t)b * Tsz + kt + nb * 16 + l15) * 64 + quad * 8;
      bf16x8 bk0 = *(const bf16x8*)(Kp);
      bf16x8 bk1 = *(const bf16x8*)(Kp + 32);
      f32x4 sacc = (f32x4){0.f, 0.f, 0.f, 0.f};
      sacc = __builtin_amdgcn_mfma_f32_16x16x32_bf16(aq0, bk0, sacc, 0, 0, 0);
      sacc = __builtin_amdgcn_mfma_f32_16x16x32_bf16(aq1, bk1, sacc, 0, 0, 0);
      S[nb] = sacc;
    }
    // ---- causal mask (diagonal tile only; wave-uniform branch) ----
    if (kt == qbase) {
#pragma unroll
      for (int nb = 0; nb < 4; nb++) {
        int kg = kt + nb * 16 + l15;
#pragma unroll
        for (int r = 0; r < 4; r++)
          if (kg > qg + r) S[nb][r] = -1e30f;
      }
    }
    // ---- online softmax (row = quad*4+r; reduce over nb regs + 16-lane group) ----
    float alpha[4], ps[4];
#pragma unroll
    for (int r = 0; r < 4; r++) {
      float t0 = fmaxf(fmaxf(S[0][r], S[1][r]), fmaxf(S[2][r], S[3][r]));
      t0 = fmaxf(t0, __shfl_xor(t0, 1, 64));
      t0 = fmaxf(t0, __shfl_xor(t0, 2, 64));
      t0 = fmaxf(t0, __shfl_xor(t0, 4, 64));
      t0 = fmaxf(t0, __shfl_xor(t0, 8, 64));
      float mn = fmaxf(m_i[r], t0);
      alpha[r] = __expf(m_i[r] - mn);
      m_i[r] = mn;
      ps[r] = 0.f;
    }
#pragma unroll
    for (int nb = 0; nb < 4; nb++) {
#pragma unroll
      for (int r = 0; r < 4; r++) {
        float p = __expf(S[nb][r] - m_i[r]);
        ps[r] += p;
        Sp[w * 16 + quad * 4 + r][nb * 16 + l15] = f2bf(p);
      }
    }
#pragma unroll
    for (int r = 0; r < 4; r++) {
      float t = ps[r];
      t += __shfl_xor(t, 1, 64);
      t += __shfl_xor(t, 2, 64);
      t += __shfl_xor(t, 4, 64);
      t += __shfl_xor(t, 8, 64);
      l_i[r] = l_i[r] * alpha[r] + t;
    }
#pragma unroll
    for (int nb = 0; nb < 4; nb++) {
#pragma unroll
      for (int r = 0; r < 4; r++) O[nb][r] *= alpha[r];
    }
    // ---- O += P V : P A-frags from own Sp rows (same-wave, waitcnt-ordered) ----
    const unsigned short* Pp = &Sp[w * 16 + l15][quad * 8];
    bf16x8 ap0 = *(const bf16x8*)(Pp);
    bf16x8 ap1 = *(const bf16x8*)(Pp + 32);
#pragma unroll
    for (int nb = 0; nb < 4; nb++) {
      const unsigned short* Vp =
          Vt + ((size_t)b * 64 + nb * 16 + l15) * Tsz + kt + quad * 8;
      bf16x8 bv0 = *(const bf16x8*)(Vp);
      bf16x8 bv1 = *(const bf16x8*)(Vp + 32);
      O[nb] = __builtin_amdgcn_mfma_f32_16x16x32_bf16(ap0, bv0, O[nb], 0, 0, 0);
      O[nb] = __builtin_amdgcn_mfma_f32_16x16x32_bf16(ap1, bv1, O[nb], 0, 0, 0);
    }
  }
  // ---- epilogue: out = O / l ----
#pragma unroll
  for (int nb = 0; nb < 4; nb++) {
#pragma unroll
    for (int r = 0; r < 4; r++) {
      out[((size_t)b * Tsz + qbase + w * 16 + quad * 4 + r) * 64 + nb * 16 + l15] =
          O[nb][r] / l_i[r];
    }
  }
}

extern "C" void kernel_launch(void* const* d_in, const int* in_sizes, int n_in,
                              void* d_out, int out_size, void* d_ws, size_t ws_size,
                              hipStream_t stream) {
  const float* x = (const float*)d_in[0];
  const float* Wq = (const float*)d_in[1];
  const float* Wk = (const float*)d_in[2];
  const float* Wv = (const float*)d_in[3];

  unsigned short* Qs = (unsigned short*)d_ws;                 // 4MB
  unsigned short* Ks = Qs + (size_t)Bsz * Tsz * 64;           // 4MB
  unsigned short* Vt = Ks + (size_t)Bsz * Tsz * 64;           // 4MB

  dim3 grid(Tsz / 64, Bsz);
  proj_kernel<<<grid, 256, 0, stream>>>(x, Wq, Wk, Wv, Qs, Ks, Vt);
  flash_kernel<<<grid, 256, 0, stream>>>(Qs, Ks, Vt, (float*)d_out);
}